// Round 10
// baseline (893.208 us; speedup 1.0000x reference)
//
#include <hip/hip_runtime.h>
#include <stdint.h>

// SNN audio classifier. 256 blocks x 1024 threads, 2 samples/block (h = tid>>9),
// 8 waves per sample, T=100 in-kernel. Round 10: same arithmetic as round 9
// (bit-identical per-output chains), work per wave halved, 16 waves/CU
// (4/SIMD, 50% occupancy) sharing one 90KB LDS fc1-weight store.

#define NB 512
#define NT 100
#define LIN 686
#define RS 71          // spool2 row stride in v2f; cols 0,69,70 are zero pads

typedef float v2f __attribute__((ext_vector_type(2)));

__device__ __forceinline__ v2f pkfma(v2f a, v2f b, v2f c) {
    v2f d;
    asm("v_pk_fma_f32 %0, %1, %2, %3" : "=v"(d) : "v"(a), "v"(b), "v"(c));
    return d;
}

__device__ __forceinline__ float dpp_add8(float x) {   // sum over 8-lane groups
    int t;
    t = __builtin_amdgcn_mov_dpp(__float_as_int(x), 0x141, 0xf, 0xf, true); // row_half_mirror
    x += __int_as_float(t);
    t = __builtin_amdgcn_mov_dpp(__float_as_int(x), 0x1B, 0xf, 0xf, true);  // quad_perm [3,2,1,0]
    x += __int_as_float(t);
    t = __builtin_amdgcn_mov_dpp(__float_as_int(x), 0xB1, 0xf, 0xf, true);  // quad_perm [1,0,3,2]
    x += __int_as_float(t);
    return x;
}

__device__ __forceinline__ float red32(float x) {      // sum over 32-lane groups
    int t;
    t = __builtin_amdgcn_mov_dpp(__float_as_int(x), 0xB1, 0xf, 0xf, true);  // xor1
    x += __int_as_float(t);
    t = __builtin_amdgcn_mov_dpp(__float_as_int(x), 0x4E, 0xf, 0xf, true);  // xor2
    x += __int_as_float(t);
    t = __builtin_amdgcn_ds_swizzle(__float_as_int(x), 0x101F);             // xor4
    x += __int_as_float(t);
    t = __builtin_amdgcn_ds_swizzle(__float_as_int(x), 0x201F);             // xor8
    x += __int_as_float(t);
    t = __builtin_amdgcn_ds_swizzle(__float_as_int(x), 0x401F);             // xor16
    x += __int_as_float(t);
    return x;
}

__global__
__attribute__((amdgpu_flat_work_group_size(1024, 1024)))
void snn_all(
    const float* __restrict__ x,
    const float* __restrict__ w1, const float* __restrict__ b1,
    const float* __restrict__ w2, const float* __restrict__ b2,
    const float* __restrict__ wf1, const float* __restrict__ bf1,
    const float* __restrict__ wf2, const float* __restrict__ bf2,
    float* __restrict__ out)
{
    // fc1 weights: f4[g*352 + i*32 + s] = {w[2g][s*22+2i], w[2g][s*22+2i+1],
    //                                      w[2g+1][s*22+2i], w[2g+1][s*22+2i+1]}
    // g in 0..15 (output pair), i in 0..10 (tap pair), s in 0..31 (channel).
    __shared__ __align__(16) float swf1r[5632 * 4];            // 90112 B, shared
    __shared__ __align__(16) float sx[2][LIN + 2];
    __shared__ __align__(16) float spool2f[2][8 * RS * 2];
    __shared__ unsigned long long sbits2[2][8][2];
    __shared__ __align__(8) float sspk3[2][32];

    const int tid  = threadIdx.x;
    const int h    = tid >> 9;
    const int t2   = tid & 511;
    const int b    = blockIdx.x * 2 + h;
    const int lane = t2 & 63;
    const int wv   = t2 >> 6;          // wave within the half: 0..7

    float* sxh    = sx[h];
    float* spoolh = spool2f[h];
    unsigned long long (*sbh)[2] = sbits2[h];
    float* sspk3h = sspk3[h];

    // ---------------- one-time init: reorder wf1 into LDS ----------------
    for (int d = tid; d < 5632; d += 1024) {
        int g = d / 352;
        int r = d - g * 352;
        int i = r >> 5;
        int s = r & 31;
        float4 v;
        v.x = wf1[(2 * g)     * 704 + s * 22 + 2 * i];
        v.y = wf1[(2 * g)     * 704 + s * 22 + 2 * i + 1];
        v.z = wf1[(2 * g + 1) * 704 + s * 22 + 2 * i];
        v.w = wf1[(2 * g + 1) * 704 + s * 22 + 2 * i + 1];
        reinterpret_cast<float4*>(swf1r)[d] = v;
    }

    // ---- phase A setup: conv1. thread = (ca = t2&15, pg = t2>>4 in 0..31) ----
    const int ca = t2 & 15;
    const int pg = t2 >> 4;
    float wA[13];
    #pragma unroll
    for (int k = 0; k < 13; ++k) wA[k] = w1[ca * 13 + k];
    v2f we0 = {wA[0], wA[1]}, we1 = {wA[2], wA[3]}, we2 = {wA[4], wA[5]},
        we3 = {wA[6], wA[7]}, we4 = {wA[8], wA[9]}, we5 = {wA[10], wA[11]};
    v2f wo0 = {wA[1], wA[2]}, wo1 = {wA[3], wA[4]}, wo2 = {wA[5], wA[6]},
        wo3 = {wA[7], wA[8]}, wo4 = {wA[9], wA[10]}, wo5 = {wA[11], wA[12]};
    const float wA0s = wA[0], wA12s = wA[12];
    const float bA = b1[ca];
    float m1a[3], m1b[3];
    #pragma unroll
    for (int j = 0; j < 3; ++j) { m1a[j] = 0.f; m1b[j] = 0.f; }

    // ---- phase B setup: conv2. wave wv owns channel quartet 4wv..4wv+3 ----
    const int ip  = lane & 7;          // row-pair (conv1 rows 2ip, 2ip+1)
    const int og  = (lane >> 3) & 3;   // output phase
    const int omh = lane >> 5;         // window triple: om = {omh, 2+omh, 4+omh}
    const int ccq = ip & 3;            // owned channel within quartet
    v2f wp0[7], wp1[7], wp2[7], wp3[7];
    #pragma unroll
    for (int k = 0; k < 7; ++k) {
        int base0 = (wv * 4 + 0) * 112 + 14 * ip + k;
        int base1 = (wv * 4 + 1) * 112 + 14 * ip + k;
        int base2 = (wv * 4 + 2) * 112 + 14 * ip + k;
        int base3 = (wv * 4 + 3) * 112 + 14 * ip + k;
        wp0[k].x = w2[base0]; wp0[k].y = w2[base0 + 7];
        wp1[k].x = w2[base1]; wp1[k].y = w2[base1 + 7];
        wp2[k].x = w2[base2]; wp2[k].y = w2[base2 + 7];
        wp3[k].x = w2[base3]; wp3[k].y = w2[base3 + 7];
    }
    const float bB = b2[wv * 4 + ccq];
    float mA = 0.f, mB = 0.f;

    // ---- phase C setup: group g = wv*2 + sub handles outputs 2g, 2g+1 ----
    const int sub = (t2 >> 5) & 1;
    const int gC  = wv * 2 + sub;
    const int s_  = t2 & 31;
    const float bC0 = bf1[2 * gC], bC1 = bf1[2 * gC + 1];
    float m30 = 0.f, m31 = 0.f;
    const int q_  = s_ >> 2;           // quartet (wave) holding channel s_
    const int cc_ = s_ & 3;            // channel within quartet

    // ---- phase D setup: fc2 ----
    float wD = 0.f, bD = 0.f;
    if (t2 < 64) {
        wD = wf2[(t2 >> 5) * 32 + (t2 & 31)];
        if ((t2 & 31) == 0) bD = bf2[t2 >> 5];
    }
    float m4 = 0.f, cnt = 0.f;

    // ---- init LDS (per half) ----
    for (int i = t2; i < 8 * RS * 2; i += 512) spoolh[i] = 0.f;  // pads stay 0
    const float* xb = x + (size_t)b * NT * LIN;
    if (t2 == 0) { sxh[0] = 0.f; sxh[LIN + 1] = 0.f; }
    sxh[1 + t2] = xb[t2];
    if (t2 < LIN - 512) sxh[1 + t2 + 512] = xb[t2 + 512];
    __syncthreads();

    const v2f* spool2v = reinterpret_cast<const v2f*>(spoolh);
    const v2f* wb0 = spool2v + ip * RS + 3 * og + 12 * omh;        // window om=omh
    const v2f* wb1 = wb0 + 24;                                     // om = 2+omh
    const v2f* wb2 = wb0 + 48;                                     // om = 4+omh
    const float4* wrow = reinterpret_cast<const float4*>(swf1r) + gC * 352 + s_;

// ===== phase A: conv1 (k13,s5,p1) + LIF1 + maxpool2; window = sx[10p .. 10p+17] =====
#define A_J(j) { \
    const int p_ = ((j) == 2) ? (64 + pg) : (pg + 32 * (j)); \
    if ((j) < 2 || pg < 4) { \
        const v2f* qv_ = reinterpret_cast<const v2f*>(sxh + 10 * p_); \
        v2f q0_ = qv_[0], q1_ = qv_[1], q2_ = qv_[2], q3_ = qv_[3], q4_ = qv_[4], \
            q5_ = qv_[5], q6_ = qv_[6], q7_ = qv_[7], q8_ = qv_[8]; \
        v2f va_ = {0.f, 0.f}, vb_ = {0.f, 0.f}; \
        va_ = pkfma(we0, q0_, va_); va_ = pkfma(we1, q1_, va_); \
        va_ = pkfma(we2, q2_, va_); va_ = pkfma(we3, q3_, va_); \
        va_ = pkfma(we4, q4_, va_); va_ = pkfma(we5, q5_, va_); \
        vb_ = pkfma(wo0, q3_, vb_); vb_ = pkfma(wo1, q4_, vb_); \
        vb_ = pkfma(wo2, q5_, vb_); vb_ = pkfma(wo3, q6_, vb_); \
        vb_ = pkfma(wo4, q7_, vb_); vb_ = pkfma(wo5, q8_, vb_); \
        float a0_ = (va_.x + va_.y) + wA12s * q6_.x; \
        float a1_ = (vb_.x + vb_.y) + wA0s * q2_.y; \
        float m0_ = m1a[(j)], mm_ = m1b[(j)]; \
        float r0_ = (m0_ > 1.f) ? 1.f : 0.f; \
        float r1_ = (mm_ > 1.f) ? 1.f : 0.f; \
        m0_ = 0.9f * m0_ + (a0_ + bA) - r0_; \
        mm_ = 0.9f * mm_ + (a1_ + bA) - r1_; \
        m1a[(j)] = m0_; m1b[(j)] = mm_; \
        spoolh[((ca >> 1) * RS + 1 + p_) * 2 + (ca & 1)] = \
            (m0_ > 1.f || mm_ > 1.f) ? 1.f : 0.f; \
    } }

// ===== phase B window: 7 v2f taps, 4 channels, dpp reduce; owner per COND =====
#define B_WIN(WB, COND, MSLOT, SPK) { \
    v2f t0_ = (WB)[0], t1_ = (WB)[1], t2v_ = (WB)[2], t3_ = (WB)[3], \
        t4_ = (WB)[4], t5_ = (WB)[5], t6_ = (WB)[6]; \
    v2f a0_ = {0.f, 0.f}, a1_ = {0.f, 0.f}, a2_ = {0.f, 0.f}, a3_ = {0.f, 0.f}; \
    a0_ = pkfma(wp0[0], t0_, a0_); a1_ = pkfma(wp1[0], t0_, a1_); \
    a2_ = pkfma(wp2[0], t0_, a2_); a3_ = pkfma(wp3[0], t0_, a3_); \
    a0_ = pkfma(wp0[1], t1_, a0_); a1_ = pkfma(wp1[1], t1_, a1_); \
    a2_ = pkfma(wp2[1], t1_, a2_); a3_ = pkfma(wp3[1], t1_, a3_); \
    a0_ = pkfma(wp0[2], t2v_, a0_); a1_ = pkfma(wp1[2], t2v_, a1_); \
    a2_ = pkfma(wp2[2], t2v_, a2_); a3_ = pkfma(wp3[2], t2v_, a3_); \
    a0_ = pkfma(wp0[3], t3_, a0_); a1_ = pkfma(wp1[3], t3_, a1_); \
    a2_ = pkfma(wp2[3], t3_, a2_); a3_ = pkfma(wp3[3], t3_, a3_); \
    a0_ = pkfma(wp0[4], t4_, a0_); a1_ = pkfma(wp1[4], t4_, a1_); \
    a2_ = pkfma(wp2[4], t4_, a2_); a3_ = pkfma(wp3[4], t4_, a3_); \
    a0_ = pkfma(wp0[5], t5_, a0_); a1_ = pkfma(wp1[5], t5_, a1_); \
    a2_ = pkfma(wp2[5], t5_, a2_); a3_ = pkfma(wp3[5], t5_, a3_); \
    a0_ = pkfma(wp0[6], t6_, a0_); a1_ = pkfma(wp1[6], t6_, a1_); \
    a2_ = pkfma(wp2[6], t6_, a2_); a3_ = pkfma(wp3[6], t6_, a3_); \
    float s0_ = dpp_add8(a0_.x + a0_.y); \
    float s1_ = dpp_add8(a1_.x + a1_.y); \
    float s2_ = dpp_add8(a2_.x + a2_.y); \
    float s3_ = dpp_add8(a3_.x + a3_.y); \
    float sc_ = (ccq == 0) ? s0_ : ((ccq == 1) ? s1_ : ((ccq == 2) ? s2_ : s3_)); \
    if (COND) { \
        float mm_ = MSLOT; \
        float rr_ = (mm_ > 1.f) ? 1.f : 0.f; \
        mm_ = 0.9f * mm_ + (sc_ + bB) - rr_; \
        MSLOT = mm_; \
        SPK = (mm_ > 1.f) ? 1.f : 0.f; \
    } }

    for (int t = 0; t < NT; ++t) {
        // ===== phase A =====
        A_J(0) A_J(1) A_J(2)
        __syncthreads();   // bar1: spool2 ready; sx free to overwrite

        // ===== prefetch x(t+1) =====
        float xp0 = 0.f, xp1 = 0.f;
        if (t + 1 < NT) {
            const float* xt = xb + (size_t)(t + 1) * LIN;
            xp0 = xt[t2];
            if (t2 < LIN - 512) xp1 = xt[t2 + 512];
        }

        // ===== phase B: conv2 + LIF2; lane's windows om = {omh, 2+omh, 4+omh} =====
        float spkA = 0.f, spkB = 0.f;
        B_WIN(wb0, ip < 4,  mA, spkA)            // o = og + 4*omh        (o in 0..7)
        B_WIN(wb1, ip >= 4, mA, spkA)            // o = og + 8 + 4*omh    (o in 8..15)
        if (omh == 0 || og < 2) {
            B_WIN(wb2, ip < 4, mB, spkB)         // o = og + 16 + 4*omh   (o in 16..21)
        }

        // publish spikes: bal1 bit l = (ch 4wv+(l&3)+..., see phase C map)
        {
            unsigned long long bal1 = __ballot(spkA > 0.5f);
            unsigned long long bal2 = __ballot(spkB > 0.5f);
            if (lane == 0) { sbh[wv][0] = bal1; sbh[wv][1] = bal2; }
        }

        // write x(t+1) (readers of sx are behind bar2+bar3)
        if (t + 1 < NT) {
            sxh[1 + t2] = xp0;
            if (t2 < LIN - 512) sxh[1 + t2 + 512] = xp1;
        }
        __syncthreads();   // bar2: sbits ready

        // ===== phase C: fc1 (704->32) + LIF3; group gC -> outputs 2gC, 2gC+1 =====
        {
            unsigned long long Ms1 = sbh[q_][0] >> cc_;
            unsigned long long Ms2 = sbh[q_][1] >> cc_;
            uint32_t W1lo = (uint32_t)Ms1, W1hi = (uint32_t)(Ms1 >> 32);
            uint32_t W2lo = (uint32_t)Ms2, W2hi = (uint32_t)(Ms2 >> 32);

            // bit(o): o<16 -> W1[(o>>2)&1], shift 4*((o>>3)&1)+8*(o&3)
            //         o>=16 -> W2[(o>>2)&1], shift 8*(o&3)
            float f[22];
            #pragma unroll
            for (int o = 0; o < 22; ++o) {
                uint32_t w = (o < 16) ? (((o >> 2) & 1) ? W1hi : W1lo)
                                      : (((o >> 2) & 1) ? W2hi : W2lo);
                int sh = (o < 16) ? (4 * ((o >> 3) & 1) + 8 * (o & 3)) : (8 * (o & 3));
                f[o] = (float)((w >> sh) & 1u);
            }

            v2f a0v = {0.f, 0.f}, a1v = {0.f, 0.f};
            #pragma unroll
            for (int i = 0; i < 11; ++i) {
                v2f fpi = (v2f){f[2 * i], f[2 * i + 1]};
                float4 wa = wrow[i * 32];
                a0v = pkfma((v2f){wa.x, wa.y}, fpi, a0v);
                a1v = pkfma((v2f){wa.z, wa.w}, fpi, a1v);
            }
            float a0 = red32(a0v.x + a0v.y);
            float a1 = red32(a1v.x + a1v.y);

            float r0 = (m30 > 1.f) ? 1.f : 0.f; m30 = 0.9f * m30 + (a0 + bC0) - r0;
            float r1 = (m31 > 1.f) ? 1.f : 0.f; m31 = 0.9f * m31 + (a1 + bC1) - r1;
            if (s_ == 0) {
                float2 st;
                st.x = (m30 > 1.f) ? 1.f : 0.f;
                st.y = (m31 > 1.f) ? 1.f : 0.f;
                *reinterpret_cast<float2*>(&sspk3h[2 * gC]) = st;
            }
        }
        __syncthreads();   // bar3: sspk3 ready

        // ===== phase D: fc2 (32->2) + LIF4 + count =====
        if (t2 < 64) {
            float v = sspk3h[t2 & 31] * wD;
            v += __shfl_xor(v, 16, 32);
            v += __shfl_xor(v, 8, 32);
            v += __shfl_xor(v, 4, 32);
            v += __shfl_xor(v, 2, 32);
            v += __shfl_xor(v, 1, 32);
            if ((t2 & 31) == 0) {
                float rr = (m4 > 1.f) ? 1.f : 0.f;
                m4 = 0.9f * m4 + (v + bD) - rr;
                if (m4 > 1.f) cnt += 1.f;
            }
        }
        // no barrier: next writer of sspk3 (phase C of t+1) is behind bar1+bar2
    }

    if (t2 == 0)  out[b * 2 + 0] = cnt;
    if (t2 == 32) out[b * 2 + 1] = cnt;
}

extern "C" void kernel_launch(void* const* d_in, const int* in_sizes, int n_in,
                              void* d_out, int out_size, void* d_ws, size_t ws_size,
                              hipStream_t stream) {
    const float* x   = (const float*)d_in[0];
    const float* w1  = (const float*)d_in[1];
    const float* b1  = (const float*)d_in[2];
    const float* w2  = (const float*)d_in[3];
    const float* b2  = (const float*)d_in[4];
    const float* wf1 = (const float*)d_in[5];
    const float* bf1 = (const float*)d_in[6];
    const float* wf2 = (const float*)d_in[7];
    const float* bf2 = (const float*)d_in[8];
    float* out = (float*)d_out;

    snn_all<<<NB / 2, 1024, 0, stream>>>(x, w1, b1, w2, b2, wf1, bf1, wf2, bf2, out);
}